// Round 4
// baseline (72.373 us; speedup 1.0000x reference)
//
#include <hip/hip_runtime.h>
#include <stdint.h>

// out[b,e] = (x_b - c_e)^T Sigma_e^{-1} (x_b - c_e);  E=32, B=8192, D=256, f32.
//  k_x   : Xbf = bf16(x)
//  k_inv : Neumann inverse Inv = I - M + M^2 - M^3 (M = Sigma - I, ||M||~0.045),
//          output in K-blocked layout [e][k>>3][n][k&7] for conflict-free k_main staging
//  k_v   : v2[e] = 2*Inv_e c_e, s[e] = c^T Inv c
//  k_main: grid(32 bt, 8 eg), 8 waves, 1 blk/CU. X tile [256][256] XOR-swizzled LDS
//          (128KB, staged once); Inv streamed per 32-k chunk via global_load_lds into
//          2x16KB double buffer (contiguous 16KB, zero-conflict reads); 32x32x16 MFMA;
//          1 barrier/chunk. out[b,e] = sum_n X[b,n]*(acc[n,b]-v2[n]) + s[e]
// R3 fix: k_main prefetch chunk offset was (t&7)*4096, must be (t&7)*8192
//         (a 32-k chunk = 4 ksl * 2048 elems). R2's overlap double-counted k.

#define NE 32
#define NB 8192
#define DD 256

typedef __bf16 bf16_t;
typedef bf16_t bf16x8 __attribute__((ext_vector_type(8)));
typedef bf16_t bf16x4 __attribute__((ext_vector_type(4)));
typedef float  f32x4  __attribute__((ext_vector_type(4)));
typedef float  f32x16 __attribute__((ext_vector_type(16)));

#define LDX 264  // k_inv M tile row stride (528B: 2-way max)
#define LDT 264  // k_inv T2t row stride

static __device__ __forceinline__ void gl2lds16(const void* g, void* l) {
  __builtin_amdgcn_global_load_lds((__attribute__((address_space(1))) void*)(g),
                                   (__attribute__((address_space(3))) void*)(l),
                                   16, 0, 0);
}

// ---------------- k_x : f32 -> bf16 ----------------
__global__ __launch_bounds__(256) void k_x(const float* __restrict__ x,
                                           bf16_t* __restrict__ Xbf) {
  int i8 = (blockIdx.x * 256 + threadIdx.x) * 8;
  f32x4 a = *(const f32x4*)(x + i8);
  f32x4 b = *(const f32x4*)(x + i8 + 4);
  bf16x8 o;
  o[0] = (bf16_t)a[0]; o[1] = (bf16_t)a[1]; o[2] = (bf16_t)a[2]; o[3] = (bf16_t)a[3];
  o[4] = (bf16_t)b[0]; o[5] = (bf16_t)b[1]; o[6] = (bf16_t)b[2]; o[7] = (bf16_t)b[3];
  *(bf16x8*)(Xbf + i8) = o;
}

// ---------------- k_inv : fused Neumann inverse ----------------
// grid (8 col-chunks, NE e), 512 threads = 8 waves. Output K-blocked layout.
__global__ __launch_bounds__(512, 2) void k_inv(const float* __restrict__ Sg,
                                                bf16_t* __restrict__ Invbf) {
  int ct = blockIdx.x;
  int e  = blockIdx.y;
  int tid = threadIdx.x, w = tid >> 6, l = tid & 63;
  __shared__ bf16_t Ml[256 * LDX];   // 132KB padded M
  __shared__ bf16_t T2t[32 * LDT];   // 16.5KB  T2t[c][n] = T2[n][cg]
  const float* Se = Sg + (size_t)e * 65536;

  // stage M = Sigma - I (f32->bf16), padded rows
#pragma unroll
  for (int i = 0; i < 16; ++i) {
    int s = i * 512 + tid;
    int row = s >> 5, c8 = (s & 31) * 8;
    f32x4 a = *(const f32x4*)(Se + row * 256 + c8);
    f32x4 b = *(const f32x4*)(Se + row * 256 + c8 + 4);
    float v[8] = {a[0], a[1], a[2], a[3], b[0], b[1], b[2], b[3]};
    int dj = row - c8;
    if (dj >= 0 && dj < 8) v[dj] -= 1.0f;
    bf16x8 o;
#pragma unroll
    for (int j = 0; j < 8; ++j) o[j] = (bf16_t)v[j];
    *(bf16x8*)&Ml[row * LDX + c8] = o;
  }
  __syncthreads();

  int rA = w * 32 + (l & 15);
  int q8 = (l >> 4) * 8;
  int cg0 = ct * 32;

  // GEMM1: V = M*M   (B-frag via symmetry: M[k][cg] = M[cg][k])
  f32x4 acc1[2][2];
#pragma unroll
  for (int i = 0; i < 2; ++i)
#pragma unroll
    for (int j = 0; j < 2; ++j) acc1[i][j] = (f32x4){0.f, 0.f, 0.f, 0.f};
#pragma unroll
  for (int kk = 0; kk < 256; kk += 32) {
    bf16x8 a0 = *(const bf16x8*)&Ml[rA * LDX + kk + q8];
    bf16x8 a1 = *(const bf16x8*)&Ml[(rA + 16) * LDX + kk + q8];
    bf16x8 b0 = *(const bf16x8*)&Ml[(cg0 + (l & 15)) * LDX + kk + q8];
    bf16x8 b1 = *(const bf16x8*)&Ml[(cg0 + 16 + (l & 15)) * LDX + kk + q8];
    acc1[0][0] = __builtin_amdgcn_mfma_f32_16x16x32_bf16(a0, b0, acc1[0][0], 0, 0, 0);
    acc1[0][1] = __builtin_amdgcn_mfma_f32_16x16x32_bf16(a0, b1, acc1[0][1], 0, 0, 0);
    acc1[1][0] = __builtin_amdgcn_mfma_f32_16x16x32_bf16(a1, b0, acc1[1][0], 0, 0, 0);
    acc1[1][1] = __builtin_amdgcn_mfma_f32_16x16x32_bf16(a1, b1, acc1[1][1], 0, 0, 0);
  }
  // T2t[c][n] = delta - M[n][cg] + V[n][cg]
#pragma unroll
  for (int nf = 0; nf < 2; ++nf) {
    int n0 = w * 32 + nf * 16 + (l >> 4) * 4;
#pragma unroll
    for (int cf = 0; cf < 2; ++cf) {
      int cl = cf * 16 + (l & 15), cg = cg0 + cl;
      bf16x4 mr = *(const bf16x4*)&Ml[cg * LDX + n0];
      f32x4 vv = acc1[nf][cf];
      bf16x4 o;
#pragma unroll
      for (int q = 0; q < 4; ++q) {
        float t2 = (((n0 + q) == cg) ? 1.0f : 0.0f) - (float)mr[q] + vv[q];
        o[q] = (bf16_t)t2;
      }
      *(bf16x4*)&T2t[cl * LDT + n0] = o;
    }
  }
  __syncthreads();

  // GEMM2: acc2 = M * T2
  f32x4 acc2[2][2];
#pragma unroll
  for (int i = 0; i < 2; ++i)
#pragma unroll
    for (int j = 0; j < 2; ++j) acc2[i][j] = (f32x4){0.f, 0.f, 0.f, 0.f};
#pragma unroll
  for (int kk = 0; kk < 256; kk += 32) {
    bf16x8 a0 = *(const bf16x8*)&Ml[rA * LDX + kk + q8];
    bf16x8 a1 = *(const bf16x8*)&Ml[(rA + 16) * LDX + kk + q8];
    bf16x8 b0 = *(const bf16x8*)&T2t[(l & 15) * LDT + kk + q8];
    bf16x8 b1 = *(const bf16x8*)&T2t[(16 + (l & 15)) * LDT + kk + q8];
    acc2[0][0] = __builtin_amdgcn_mfma_f32_16x16x32_bf16(a0, b0, acc2[0][0], 0, 0, 0);
    acc2[0][1] = __builtin_amdgcn_mfma_f32_16x16x32_bf16(a0, b1, acc2[0][1], 0, 0, 0);
    acc2[1][0] = __builtin_amdgcn_mfma_f32_16x16x32_bf16(a1, b0, acc2[1][0], 0, 0, 0);
    acc2[1][1] = __builtin_amdgcn_mfma_f32_16x16x32_bf16(a1, b1, acc2[1][1], 0, 0, 0);
  }
  // Inv[n][cg] = delta - acc2, K-blocked layout: elem(n,c) at (c>>3)*2048 + n*8 + (c&7)
  bf16_t* Ce = Invbf + (size_t)e * 65536;
#pragma unroll
  for (int nf = 0; nf < 2; ++nf) {
    int n0 = w * 32 + nf * 16 + (l >> 4) * 4;
#pragma unroll
    for (int cf = 0; cf < 2; ++cf) {
      int cg = cg0 + cf * 16 + (l & 15);
#pragma unroll
      for (int q = 0; q < 4; ++q) {
        float vv = (((n0 + q) == cg) ? 1.0f : 0.0f) - acc2[nf][cf][q];
        Ce[(cg >> 3) * 2048 + (n0 + q) * 8 + (cg & 7)] = (bf16_t)vv;
      }
    }
  }
}

// ---------------- k_v : v2 = 2*Inv*c, s = c^T Inv c ----------------
__global__ __launch_bounds__(256) void k_v(const bf16_t* __restrict__ Invbf,
                                           const float* __restrict__ Cent,
                                           float* __restrict__ v2,
                                           float* __restrict__ s_out) {
  int e = blockIdx.x, d = threadIdx.x;
  __shared__ float cl[256];
  __shared__ float ps[256];
  cl[d] = Cent[e * 256 + d];
  __syncthreads();
  const bf16_t* Ie = Invbf + (size_t)e * 65536 + d * 8;  // row d, K-blocked layout
  float acc = 0.f;
#pragma unroll
  for (int ksl = 0; ksl < 32; ++ksl) {
    bf16x8 r = *(const bf16x8*)(Ie + ksl * 2048);
#pragma unroll
    for (int j = 0; j < 8; ++j) acc += (float)r[j] * cl[ksl * 8 + j];
  }
  v2[e * 256 + d] = 2.0f * acc;
  ps[d] = cl[d] * acc;
  __syncthreads();
  for (int off = 128; off > 0; off >>= 1) {
    if (d < off) ps[d] += ps[d + off];
    __syncthreads();
  }
  if (d == 0) s_out[e] = ps[0];
}

// ---------------- k_main ----------------
// grid (32 bt, 8 eg), 512 thr = 8 waves (2 wn x 4 wb), e-loop of 4 folded into t=0..31.
__global__ __launch_bounds__(512, 2) void k_main(const bf16_t* __restrict__ Xbf,
                                                 const bf16_t* __restrict__ Invbf,
                                                 const float* __restrict__ v2g,
                                                 const float* __restrict__ sg,
                                                 float* __restrict__ out) {
  int bt = blockIdx.x;
  int eg = blockIdx.y;
  int tid = threadIdx.x, w = tid >> 6, l = tid & 63;
  __shared__ bf16_t Xl[65536];      // [256][256] XOR-swizzled (byte ^= (row&7)<<4)
  __shared__ bf16_t Invl[2][8192];  // double-buffered chunk: [4 ksl][256 n][8 k]

  const bf16_t* Xg = Xbf + (size_t)bt * 65536;
  char* Xb = (char*)Xl;

  // ---- one-time X stage: reg-staged, swizzled write ----
#pragma unroll
  for (int p = 0; p < 16; p += 4) {
    f32x4 t0[4];
#pragma unroll
    for (int i = 0; i < 4; ++i) {
      int s = (p + i) * 512 + tid;
      int row = s >> 5, c16 = s & 31;
      t0[i] = *(const f32x4*)(Xg + row * 256 + c16 * 8);
    }
#pragma unroll
    for (int i = 0; i < 4; ++i) {
      int s = (p + i) * 512 + tid;
      int row = s >> 5, c16 = s & 31;
      int byte = (row * 512 + c16 * 16) ^ ((row & 7) << 4);
      *(f32x4*)(Xb + byte) = t0[i];
    }
  }

  // ---- prologue: stage chunk 0 (contiguous 16KB) ----
  {
    const bf16_t* src = Invbf + (size_t)(eg * 4) * 65536;
    bf16_t* dst = (bf16_t*)Invl[0];
    gl2lds16(src + w * 512 + l * 8,        dst + w * 512);
    gl2lds16(src + 4096 + w * 512 + l * 8, dst + 4096 + w * 512);
  }
  __syncthreads();

  int wn = w >> 2, wb = w & 3;
  int lrow = l & 31, lhalf = l >> 5;
  int nbase = wn * 128;
  int bbase = wb * 64;

  f32x16 acc[4][2];
#pragma unroll
  for (int nf = 0; nf < 4; ++nf)
#pragma unroll
    for (int cf = 0; cf < 2; ++cf)
#pragma unroll
      for (int q = 0; q < 16; ++q) acc[nf][cf][q] = 0.f;

  for (int t = 0; t < 32; ++t) {
    int kk = (t & 7) * 32;
    int cur = t & 1;
    if (t < 31) {  // prefetch chunk t+1 into other buffer (chunk = 8192 elems = 16KB)
      int tn = t + 1;
      const bf16_t* src = Invbf + (size_t)(eg * 4 + (tn >> 3)) * 65536 + (tn & 7) * 8192;
      bf16_t* dst = (bf16_t*)Invl[tn & 1];
      gl2lds16(src + w * 512 + l * 8,        dst + w * 512);
      gl2lds16(src + 4096 + w * 512 + l * 8, dst + 4096 + w * 512);
    }
    const bf16_t* Ib = (const bf16_t*)Invl[cur];
    bf16x8 af[2][4], bfr[2][2];
#pragma unroll
    for (int s = 0; s < 2; ++s) {
#pragma unroll
      for (int nf = 0; nf < 4; ++nf)
        af[s][nf] = *(const bf16x8*)(Ib + (s * 2 + lhalf) * 2048 + (nbase + nf * 32 + lrow) * 8);
#pragma unroll
      for (int cf = 0; cf < 2; ++cf) {
        int b = bbase + cf * 32 + lrow;
        int byte = (b * 512 + (kk + s * 16 + lhalf * 8) * 2) ^ ((b & 7) << 4);
        bfr[s][cf] = *(const bf16x8*)(Xb + byte);
      }
    }
#pragma unroll
    for (int s = 0; s < 2; ++s)
#pragma unroll
      for (int nf = 0; nf < 4; ++nf)
#pragma unroll
        for (int cf = 0; cf < 2; ++cf)
          acc[nf][cf] = __builtin_amdgcn_mfma_f32_32x32x16_bf16(af[s][nf], bfr[s][cf], acc[nf][cf], 0, 0, 0);

    if ((t & 7) == 7) {  // e-epilogue
      int e = eg * 4 + (t >> 3);
      float bsum[2] = {0.f, 0.f};
#pragma unroll
      for (int nf = 0; nf < 4; ++nf)
#pragma unroll
        for (int g = 0; g < 4; ++g) {
          int n0 = nbase + nf * 32 + 8 * g + 4 * lhalf;
          f32x4 vv = *(const f32x4*)(v2g + e * 256 + n0);
#pragma unroll
          for (int cf = 0; cf < 2; ++cf) {
            int b = bbase + cf * 32 + lrow;
            int byte = (b * 512 + n0 * 2) ^ ((b & 7) << 4);
            bf16x4 xr = *(const bf16x4*)(Xb + byte);
#pragma unroll
            for (int q = 0; q < 4; ++q)
              bsum[cf] += (float)xr[q] * (acc[nf][cf][g * 4 + q] - vv[q]);
          }
        }
      __syncthreads();  // all reads of Invl[cur] done -> reuse as reduction scratch
      float* red = (float*)Invl[cur];  // [2][256] f32
#pragma unroll
      for (int cf = 0; cf < 2; ++cf) {
        float r = bsum[cf];
        r += __shfl_xor(r, 32);
        if (lhalf == 0) red[wn * 256 + bbase + cf * 32 + lrow] = r;
      }
      __syncthreads();
      if (tid < 256) {
        float res = sg[e] + red[tid] + red[256 + tid];
        out[(size_t)(bt * 256 + tid) * 32 + e] = res;
      }
#pragma unroll
      for (int nf = 0; nf < 4; ++nf)
#pragma unroll
        for (int cf = 0; cf < 2; ++cf)
#pragma unroll
          for (int q = 0; q < 16; ++q) acc[nf][cf][q] = 0.f;
    }
    __syncthreads();  // chunk t+1 staged & visible; red safe from next prefetch
  }
}

extern "C" void kernel_launch(void* const* d_in, const int* in_sizes, int n_in,
                              void* d_out, int out_size, void* d_ws, size_t ws_size,
                              hipStream_t stream) {
  const float* x    = (const float*)d_in[0];
  const float* cent = (const float*)d_in[1];
  const float* sig  = (const float*)d_in[2];
  float* out = (float*)d_out;

  char* ws = (char*)d_ws;
  bf16_t* Xbf   = (bf16_t*)(ws);                 // 4MB
  bf16_t* Invbf = (bf16_t*)(ws + (4ull << 20));  // 4MB (K-blocked layout)
  float*  v2    = (float*)(ws + (8ull << 20));   // 32KB
  float*  sArr  = (float*)(ws + (8ull << 20) + 32768);

  k_x   <<<dim3(1024),   dim3(256), 0, stream>>>(x, Xbf);
  k_inv <<<dim3(8, NE),  dim3(512), 0, stream>>>(sig, Invbf);
  k_v   <<<dim3(NE),     dim3(256), 0, stream>>>(Invbf, cent, v2, sArr);
  k_main<<<dim3(32, 8),  dim3(512), 0, stream>>>(Xbf, Invbf, v2, sArr, out);
}